// Round 10
// baseline (448.275 us; speedup 1.0000x reference)
//
#include <hip/hip_runtime.h>
#include <hip/hip_bf16.h>

#define T_TOK 2048
#define HDIM  2048
#define FDIM  1024
#define NEXP  8
#define KSEL  2
#define NENT  (T_TOK*KSEL)   // 4096 routing entries
#define WMAX  24             // max 256-row work items

typedef __attribute__((ext_vector_type(8))) short   short8v;
typedef __attribute__((ext_vector_type(4))) float   floatx4;
typedef __attribute__((ext_vector_type(4))) unsigned short ushort4v;

__device__ __forceinline__ unsigned short f2bf(float f) {
  unsigned int u = __builtin_bit_cast(unsigned int, f);
  u += 0x7FFFu + ((u >> 16) & 1u);
  return (unsigned short)(u >> 16);
}

__device__ __forceinline__ short8v cvt8(floatx4 v0, floatx4 v1, float sc) {
  short8v r = { (short)f2bf(v0.x*sc), (short)f2bf(v0.y*sc),
                (short)f2bf(v0.z*sc), (short)f2bf(v0.w*sc),
                (short)f2bf(v1.x*sc), (short)f2bf(v1.y*sc),
                (short)f2bf(v1.z*sc), (short)f2bf(v1.w*sc) };
  return r;
}

// ---- workspace layout ----
// wsI[0:8) cnt | wsI[8:16) cursor | wsI[16:24) offsets | wsI[24] nWork
// wsI[48:72) work list (e<<8 | block256)
// wsI[128:128+4096) entry token | (float*)[4096] entry weight
// byte 65536: hidden_bf (8 MiB) | act (8 MiB)
#define ETOK_OFF 128

__global__ void k_count(const int* __restrict__ ids, int* __restrict__ wsI) {
  int g = blockIdx.x * 256 + threadIdx.x;
  if (g < NENT) atomicAdd(&wsI[ids[g] & 7], 1);
}

__global__ void k_scan(int* __restrict__ wsI) {
  int s = 0, nW = 0;
  int* wl = wsI + 48;
  for (int e = 0; e < NEXP; e++) {
    wsI[16 + e] = s;
    int c = wsI[e];
    s += c;
    int nb = (c + 255) >> 8;
    for (int sb = 0; sb < nb; sb++) wl[nW++] = (e << 8) | sb;
  }
  wsI[24] = nW;
}

__global__ void k_scatter(const int* __restrict__ ids, const float* __restrict__ tw,
                          int* __restrict__ wsI) {
  int g = blockIdx.x * 256 + threadIdx.x;
  if (g >= NENT) return;
  int e = ids[g] & 7;
  int pos = atomicAdd(&wsI[8 + e], 1);
  int idx = wsI[16 + e] + pos;
  int*   etok = wsI + ETOK_OFF;
  float* ew   = (float*)(wsI + ETOK_OFF + NENT);
  etok[idx] = g >> 1;
  ew[idx]   = tw[g];
}

__global__ __launch_bounds__(256) void k_cast_h(const float* __restrict__ h,
                                                unsigned short* __restrict__ o) {
  const int N = T_TOK * HDIM / 8;
  for (int c = blockIdx.x * 256 + threadIdx.x; c < N; c += 2048 * 256) {
    const floatx4 v0 = *(const floatx4*)(h + (size_t)c * 8);
    const floatx4 v1 = *(const floatx4*)(h + (size_t)c * 8 + 4);
    *(short8v*)(o + (size_t)c * 8) = cvt8(v0, v1, 1.f);
  }
}

// ---- GEMM1: act = silu(h@Wg^T)*(h@Wu^T) ----
// NO LDS, NO barriers. Each wave independent: 64 entry-rows x 32 act cols.
// A: bf16 fragments direct from hb (gather hoisted into 4 base ptrs).
// B: fp32 direct loads + fused scale*cvt in registers. grid (WMAX, 32).
__global__ __launch_bounds__(256, 2) void k_gemm1n(
    const unsigned short* __restrict__ hb,
    const float* __restrict__ wgu,
    const float* __restrict__ sgu,
    const int* __restrict__ wsI,
    unsigned short* __restrict__ act)
{
  if ((int)blockIdx.x >= wsI[24]) return;
  const int item = wsI[48 + blockIdx.x];
  const int e    = item >> 8;
  const int r0   = (item & 255) << 8;
  const int cnt  = wsI[e];
  const int off  = wsI[16 + e];
  const int c0   = blockIdx.y * 32;
  const int* etok = wsI + ETOK_OFF;

  const int tid = threadIdx.x, lane = tid & 63, w = tid >> 6;
  const int kg = lane >> 4, l15 = lane & 15;
  const int wm = r0 + w * 64;
  if (wm >= cnt) return;                      // wave-uniform; no barriers in kernel

  const unsigned short* abase[4];
#pragma unroll
  for (int m = 0; m < 4; m++) {
    int ent = wm + m * 16 + l15; if (ent >= cnt) ent = cnt - 1;
    abase[m] = hb + (size_t)etok[off + ent] * HDIM + kg * 8;
  }
  const float* bbase[4];
  int sidx[4];
#pragma unroll
  for (int n = 0; n < 4; n++) {
    int gr = (n < 2) ? (c0 + n * 16 + l15) : (1024 + c0 + (n - 2) * 16 + l15);
    bbase[n] = wgu + ((size_t)e * 2048 + gr) * HDIM + kg * 8;
    sidx[n]  = e * 256 + (gr >> 7) * 16;
  }

  floatx4 acc[4][4] = {};

  for (int t = 0; t < 32; ++t) {
    const int ka = t * 64;
    float s0 = sgu[sidx[0] + (ka >> 7)];
    float s1 = sgu[sidx[1] + (ka >> 7)];
    float s2 = sgu[sidx[2] + (ka >> 7)];
    float s3 = sgu[sidx[3] + (ka >> 7)];

    short8v a0k0 = *(const short8v*)(abase[0] + ka);
    short8v a1k0 = *(const short8v*)(abase[1] + ka);
    short8v a2k0 = *(const short8v*)(abase[2] + ka);
    short8v a3k0 = *(const short8v*)(abase[3] + ka);
    short8v a0k1 = *(const short8v*)(abase[0] + ka + 32);
    short8v a1k1 = *(const short8v*)(abase[1] + ka + 32);
    short8v a2k1 = *(const short8v*)(abase[2] + ka + 32);
    short8v a3k1 = *(const short8v*)(abase[3] + ka + 32);

    short8v b0k0, b1k0, b2k0, b3k0, b0k1, b1k1, b2k1, b3k1;
    {
      floatx4 v0, v1;
      v0 = *(const floatx4*)(bbase[0] + ka);      v1 = *(const floatx4*)(bbase[0] + ka + 4);
      b0k0 = cvt8(v0, v1, s0);
      v0 = *(const floatx4*)(bbase[0] + ka + 32); v1 = *(const floatx4*)(bbase[0] + ka + 36);
      b0k1 = cvt8(v0, v1, s0);
      v0 = *(const floatx4*)(bbase[1] + ka);      v1 = *(const floatx4*)(bbase[1] + ka + 4);
      b1k0 = cvt8(v0, v1, s1);
      v0 = *(const floatx4*)(bbase[1] + ka + 32); v1 = *(const floatx4*)(bbase[1] + ka + 36);
      b1k1 = cvt8(v0, v1, s1);
      v0 = *(const floatx4*)(bbase[2] + ka);      v1 = *(const floatx4*)(bbase[2] + ka + 4);
      b2k0 = cvt8(v0, v1, s2);
      v0 = *(const floatx4*)(bbase[2] + ka + 32); v1 = *(const floatx4*)(bbase[2] + ka + 36);
      b2k1 = cvt8(v0, v1, s2);
      v0 = *(const floatx4*)(bbase[3] + ka);      v1 = *(const floatx4*)(bbase[3] + ka + 4);
      b3k0 = cvt8(v0, v1, s3);
      v0 = *(const floatx4*)(bbase[3] + ka + 32); v1 = *(const floatx4*)(bbase[3] + ka + 36);
      b3k1 = cvt8(v0, v1, s3);
    }

    acc[0][0] = __builtin_amdgcn_mfma_f32_16x16x32_bf16(a0k0, b0k0, acc[0][0], 0, 0, 0);
    acc[0][1] = __builtin_amdgcn_mfma_f32_16x16x32_bf16(a0k0, b1k0, acc[0][1], 0, 0, 0);
    acc[0][2] = __builtin_amdgcn_mfma_f32_16x16x32_bf16(a0k0, b2k0, acc[0][2], 0, 0, 0);
    acc[0][3] = __builtin_amdgcn_mfma_f32_16x16x32_bf16(a0k0, b3k0, acc[0][3], 0, 0, 0);
    acc[1][0] = __builtin_amdgcn_mfma_f32_16x16x32_bf16(a1k0, b0k0, acc[1][0], 0, 0, 0);
    acc[1][1] = __builtin_amdgcn_mfma_f32_16x16x32_bf16(a1k0, b1k0, acc[1][1], 0, 0, 0);
    acc[1][2] = __builtin_amdgcn_mfma_f32_16x16x32_bf16(a1k0, b2k0, acc[1][2], 0, 0, 0);
    acc[1][3] = __builtin_amdgcn_mfma_f32_16x16x32_bf16(a1k0, b3k0, acc[1][3], 0, 0, 0);
    acc[2][0] = __builtin_amdgcn_mfma_f32_16x16x32_bf16(a2k0, b0k0, acc[2][0], 0, 0, 0);
    acc[2][1] = __builtin_amdgcn_mfma_f32_16x16x32_bf16(a2k0, b1k0, acc[2][1], 0, 0, 0);
    acc[2][2] = __builtin_amdgcn_mfma_f32_16x16x32_bf16(a2k0, b2k0, acc[2][2], 0, 0, 0);
    acc[2][3] = __builtin_amdgcn_mfma_f32_16x16x32_bf16(a2k0, b3k0, acc[2][3], 0, 0, 0);
    acc[3][0] = __builtin_amdgcn_mfma_f32_16x16x32_bf16(a3k0, b0k0, acc[3][0], 0, 0, 0);
    acc[3][1] = __builtin_amdgcn_mfma_f32_16x16x32_bf16(a3k0, b1k0, acc[3][1], 0, 0, 0);
    acc[3][2] = __builtin_amdgcn_mfma_f32_16x16x32_bf16(a3k0, b2k0, acc[3][2], 0, 0, 0);
    acc[3][3] = __builtin_amdgcn_mfma_f32_16x16x32_bf16(a3k0, b3k0, acc[3][3], 0, 0, 0);

    acc[0][0] = __builtin_amdgcn_mfma_f32_16x16x32_bf16(a0k1, b0k1, acc[0][0], 0, 0, 0);
    acc[0][1] = __builtin_amdgcn_mfma_f32_16x16x32_bf16(a0k1, b1k1, acc[0][1], 0, 0, 0);
    acc[0][2] = __builtin_amdgcn_mfma_f32_16x16x32_bf16(a0k1, b2k1, acc[0][2], 0, 0, 0);
    acc[0][3] = __builtin_amdgcn_mfma_f32_16x16x32_bf16(a0k1, b3k1, acc[0][3], 0, 0, 0);
    acc[1][0] = __builtin_amdgcn_mfma_f32_16x16x32_bf16(a1k1, b0k1, acc[1][0], 0, 0, 0);
    acc[1][1] = __builtin_amdgcn_mfma_f32_16x16x32_bf16(a1k1, b1k1, acc[1][1], 0, 0, 0);
    acc[1][2] = __builtin_amdgcn_mfma_f32_16x16x32_bf16(a1k1, b2k1, acc[1][2], 0, 0, 0);
    acc[1][3] = __builtin_amdgcn_mfma_f32_16x16x32_bf16(a1k1, b3k1, acc[1][3], 0, 0, 0);
    acc[2][0] = __builtin_amdgcn_mfma_f32_16x16x32_bf16(a2k1, b0k1, acc[2][0], 0, 0, 0);
    acc[2][1] = __builtin_amdgcn_mfma_f32_16x16x32_bf16(a2k1, b1k1, acc[2][1], 0, 0, 0);
    acc[2][2] = __builtin_amdgcn_mfma_f32_16x16x32_bf16(a2k1, b2k1, acc[2][2], 0, 0, 0);
    acc[2][3] = __builtin_amdgcn_mfma_f32_16x16x32_bf16(a2k1, b3k1, acc[2][3], 0, 0, 0);
    acc[3][0] = __builtin_amdgcn_mfma_f32_16x16x32_bf16(a3k1, b0k1, acc[3][0], 0, 0, 0);
    acc[3][1] = __builtin_amdgcn_mfma_f32_16x16x32_bf16(a3k1, b1k1, acc[3][1], 0, 0, 0);
    acc[3][2] = __builtin_amdgcn_mfma_f32_16x16x32_bf16(a3k1, b2k1, acc[3][2], 0, 0, 0);
    acc[3][3] = __builtin_amdgcn_mfma_f32_16x16x32_bf16(a3k1, b3k1, acc[3][3], 0, 0, 0);
  }

#pragma unroll
  for (int m = 0; m < 4; m++) {
    int rbase = wm + m * 16 + kg * 4;
#pragma unroll
    for (int reg = 0; reg < 4; reg++) {
      int rr = rbase + reg;
      if (rr < cnt) {
#pragma unroll
        for (int n = 0; n < 2; n++) {
          float g = acc[m][n][reg];
          float u = acc[m][n + 2][reg];
          float a = g / (1.f + __expf(-g)) * u;
          act[(size_t)(off + rr) * FDIM + c0 + n * 16 + l15] = f2bf(a);
        }
      }
    }
  }
}

// ---- GEMM2: out[tok] += w_entry * (act @ Wdn^T); same barrier-free structure ----
// wave: 64 entry-rows x 64 h-cols; grid (WMAX, 32). Atomic epilogue.
__global__ __launch_bounds__(256, 2) void k_gemm2n(
    const float* __restrict__ wdn,
    const float* __restrict__ sdn,
    const int* __restrict__ wsI,
    const unsigned short* __restrict__ act,
    float* __restrict__ out)
{
  if ((int)blockIdx.x >= wsI[24]) return;
  const int item = wsI[48 + blockIdx.x];
  const int e    = item >> 8;
  const int r0   = (item & 255) << 8;
  const int cnt  = wsI[e];
  const int off  = wsI[16 + e];
  const int c0   = blockIdx.y * 64;
  const int* etok = wsI + ETOK_OFF;
  const float* ew = (const float*)(wsI + ETOK_OFF + NENT);

  const int tid = threadIdx.x, lane = tid & 63, w = tid >> 6;
  const int kg = lane >> 4, l15 = lane & 15;
  const int wm = r0 + w * 64;
  if (wm >= cnt) return;

  const unsigned short* abase[4];
#pragma unroll
  for (int m = 0; m < 4; m++) {
    int ent = wm + m * 16 + l15; if (ent >= cnt) ent = cnt - 1;
    abase[m] = act + (size_t)(off + ent) * FDIM + kg * 8;
  }
  const float* bbase[4];
  int sidx[4];
#pragma unroll
  for (int n = 0; n < 4; n++) {
    int gr = c0 + n * 16 + l15;
    bbase[n] = wdn + ((size_t)e * 2048 + gr) * FDIM + kg * 8;
    sidx[n]  = e * 128 + (gr >> 7) * 8;
  }

  floatx4 acc[4][4] = {};

  for (int t = 0; t < 16; ++t) {
    const int ka = t * 64;
    float s0 = sdn[sidx[0] + (ka >> 7)];
    float s1 = sdn[sidx[1] + (ka >> 7)];
    float s2 = sdn[sidx[2] + (ka >> 7)];
    float s3 = sdn[sidx[3] + (ka >> 7)];

    short8v a0k0 = *(const short8v*)(abase[0] + ka);
    short8v a1k0 = *(const short8v*)(abase[1] + ka);
    short8v a2k0 = *(const short8v*)(abase[2] + ka);
    short8v a3k0 = *(const short8v*)(abase[3] + ka);
    short8v a0k1 = *(const short8v*)(abase[0] + ka + 32);
    short8v a1k1 = *(const short8v*)(abase[1] + ka + 32);
    short8v a2k1 = *(const short8v*)(abase[2] + ka + 32);
    short8v a3k1 = *(const short8v*)(abase[3] + ka + 32);

    short8v b0k0, b1k0, b2k0, b3k0, b0k1, b1k1, b2k1, b3k1;
    {
      floatx4 v0, v1;
      v0 = *(const floatx4*)(bbase[0] + ka);      v1 = *(const floatx4*)(bbase[0] + ka + 4);
      b0k0 = cvt8(v0, v1, s0);
      v0 = *(const floatx4*)(bbase[0] + ka + 32); v1 = *(const floatx4*)(bbase[0] + ka + 36);
      b0k1 = cvt8(v0, v1, s0);
      v0 = *(const floatx4*)(bbase[1] + ka);      v1 = *(const floatx4*)(bbase[1] + ka + 4);
      b1k0 = cvt8(v0, v1, s1);
      v0 = *(const floatx4*)(bbase[1] + ka + 32); v1 = *(const floatx4*)(bbase[1] + ka + 36);
      b1k1 = cvt8(v0, v1, s1);
      v0 = *(const floatx4*)(bbase[2] + ka);      v1 = *(const floatx4*)(bbase[2] + ka + 4);
      b2k0 = cvt8(v0, v1, s2);
      v0 = *(const floatx4*)(bbase[2] + ka + 32); v1 = *(const floatx4*)(bbase[2] + ka + 36);
      b2k1 = cvt8(v0, v1, s2);
      v0 = *(const floatx4*)(bbase[3] + ka);      v1 = *(const floatx4*)(bbase[3] + ka + 4);
      b3k0 = cvt8(v0, v1, s3);
      v0 = *(const floatx4*)(bbase[3] + ka + 32); v1 = *(const floatx4*)(bbase[3] + ka + 36);
      b3k1 = cvt8(v0, v1, s3);
    }

    acc[0][0] = __builtin_amdgcn_mfma_f32_16x16x32_bf16(a0k0, b0k0, acc[0][0], 0, 0, 0);
    acc[0][1] = __builtin_amdgcn_mfma_f32_16x16x32_bf16(a0k0, b1k0, acc[0][1], 0, 0, 0);
    acc[0][2] = __builtin_amdgcn_mfma_f32_16x16x32_bf16(a0k0, b2k0, acc[0][2], 0, 0, 0);
    acc[0][3] = __builtin_amdgcn_mfma_f32_16x16x32_bf16(a0k0, b3k0, acc[0][3], 0, 0, 0);
    acc[1][0] = __builtin_amdgcn_mfma_f32_16x16x32_bf16(a1k0, b0k0, acc[1][0], 0, 0, 0);
    acc[1][1] = __builtin_amdgcn_mfma_f32_16x16x32_bf16(a1k0, b1k0, acc[1][1], 0, 0, 0);
    acc[1][2] = __builtin_amdgcn_mfma_f32_16x16x32_bf16(a1k0, b2k0, acc[1][2], 0, 0, 0);
    acc[1][3] = __builtin_amdgcn_mfma_f32_16x16x32_bf16(a1k0, b3k0, acc[1][3], 0, 0, 0);
    acc[2][0] = __builtin_amdgcn_mfma_f32_16x16x32_bf16(a2k0, b0k0, acc[2][0], 0, 0, 0);
    acc[2][1] = __builtin_amdgcn_mfma_f32_16x16x32_bf16(a2k0, b1k0, acc[2][1], 0, 0, 0);
    acc[2][2] = __builtin_amdgcn_mfma_f32_16x16x32_bf16(a2k0, b2k0, acc[2][2], 0, 0, 0);
    acc[2][3] = __builtin_amdgcn_mfma_f32_16x16x32_bf16(a2k0, b3k0, acc[2][3], 0, 0, 0);
    acc[3][0] = __builtin_amdgcn_mfma_f32_16x16x32_bf16(a3k0, b0k0, acc[3][0], 0, 0, 0);
    acc[3][1] = __builtin_amdgcn_mfma_f32_16x16x32_bf16(a3k0, b1k0, acc[3][1], 0, 0, 0);
    acc[3][2] = __builtin_amdgcn_mfma_f32_16x16x32_bf16(a3k0, b2k0, acc[3][2], 0, 0, 0);
    acc[3][3] = __builtin_amdgcn_mfma_f32_16x16x32_bf16(a3k0, b3k0, acc[3][3], 0, 0, 0);

    acc[0][0] = __builtin_amdgcn_mfma_f32_16x16x32_bf16(a0k1, b0k1, acc[0][0], 0, 0, 0);
    acc[0][1] = __builtin_amdgcn_mfma_f32_16x16x32_bf16(a0k1, b1k1, acc[0][1], 0, 0, 0);
    acc[0][2] = __builtin_amdgcn_mfma_f32_16x16x32_bf16(a0k1, b2k1, acc[0][2], 0, 0, 0);
    acc[0][3] = __builtin_amdgcn_mfma_f32_16x16x32_bf16(a0k1, b3k1, acc[0][3], 0, 0, 0);
    acc[1][0] = __builtin_amdgcn_mfma_f32_16x16x32_bf16(a1k1, b0k1, acc[1][0], 0, 0, 0);
    acc[1][1] = __builtin_amdgcn_mfma_f32_16x16x32_bf16(a1k1, b1k1, acc[1][1], 0, 0, 0);
    acc[1][2] = __builtin_amdgcn_mfma_f32_16x16x32_bf16(a1k1, b2k1, acc[1][2], 0, 0, 0);
    acc[1][3] = __builtin_amdgcn_mfma_f32_16x16x32_bf16(a1k1, b3k1, acc[1][3], 0, 0, 0);
    acc[2][0] = __builtin_amdgcn_mfma_f32_16x16x32_bf16(a2k1, b0k1, acc[2][0], 0, 0, 0);
    acc[2][1] = __builtin_amdgcn_mfma_f32_16x16x32_bf16(a2k1, b1k1, acc[2][1], 0, 0, 0);
    acc[2][2] = __builtin_amdgcn_mfma_f32_16x16x32_bf16(a2k1, b2k1, acc[2][2], 0, 0, 0);
    acc[2][3] = __builtin_amdgcn_mfma_f32_16x16x32_bf16(a2k1, b3k1, acc[2][3], 0, 0, 0);
    acc[3][0] = __builtin_amdgcn_mfma_f32_16x16x32_bf16(a3k1, b0k1, acc[3][0], 0, 0, 0);
    acc[3][1] = __builtin_amdgcn_mfma_f32_16x16x32_bf16(a3k1, b1k1, acc[3][1], 0, 0, 0);
    acc[3][2] = __builtin_amdgcn_mfma_f32_16x16x32_bf16(a3k1, b2k1, acc[3][2], 0, 0, 0);
    acc[3][3] = __builtin_amdgcn_mfma_f32_16x16x32_bf16(a3k1, b3k1, acc[3][3], 0, 0, 0);
  }

#pragma unroll
  for (int m = 0; m < 4; m++) {
    int rbase = wm + m * 16 + kg * 4;
#pragma unroll
    for (int reg = 0; reg < 4; reg++) {
      int rr = rbase + reg;
      if (rr < cnt) {
        int tok   = etok[off + rr];
        float wgt = ew[off + rr];
#pragma unroll
        for (int n = 0; n < 4; n++)
          atomicAdd(&out[(size_t)tok * HDIM + c0 + n * 16 + l15], wgt * acc[m][n][reg]);
      }
    }
  }
}

// ================= fallback (round-1 passing kernels) =================
__global__ __launch_bounds__(256) void k_gemm1_fb(
    const float* __restrict__ hidden, const float* __restrict__ wgu,
    const float* __restrict__ sgu, const int* __restrict__ wsI,
    unsigned short* __restrict__ act)
{
  const int e = blockIdx.y; const int cnt = wsI[e];
  const int r0 = blockIdx.x * 128; if (r0 >= cnt) return;
  const int off = wsI[16 + e]; const int c0 = blockIdx.z * 64;
  const int* etok = wsI + ETOK_OFF;
  __shared__ unsigned short As[128][40]; __shared__ unsigned short Bs[128][40];
  const int tid = threadIdx.x, lane = tid & 63, wv = tid >> 6;
  const int wr = (wv >> 1) * 64, wc = wv & 1, kg = lane >> 4, l15 = lane & 15;
  floatx4 acc[4][4] = {};
  for (int k0 = 0; k0 < HDIM; k0 += 32) {
#pragma unroll
    for (int c = tid; c < 1024; c += 256) {
      int row = c >> 3, k4 = c & 7;
      int rg = r0 + row; if (rg >= cnt) rg = cnt - 1;
      int tok = etok[off + rg];
      const floatx4 v = *(const floatx4*)&hidden[(size_t)tok * HDIM + k0 + k4 * 4];
      ushort4v o = { f2bf(v.x), f2bf(v.y), f2bf(v.z), f2bf(v.w) };
      *(ushort4v*)&As[row][k4 * 4] = o;
    }
#pragma unroll
    for (int c = tid; c < 1024; c += 256) {
      int row = c >> 3, k4 = c & 7;
      int gr = (row < 64) ? (c0 + row) : (FDIM + c0 + row - 64);
      float s = sgu[e * 256 + (gr >> 7) * 16 + (k0 >> 7)];
      const floatx4 v = *(const floatx4*)&wgu[((size_t)e * 2048 + gr) * HDIM + k0 + k4 * 4];
      ushort4v o = { f2bf(v.x * s), f2bf(v.y * s), f2bf(v.z * s), f2bf(v.w * s) };
      *(ushort4v*)&Bs[row][k4 * 4] = o;
    }
    __syncthreads();
    short8v a[4], b[4];
#pragma unroll
    for (int m = 0; m < 4; m++) a[m] = *(const short8v*)&As[wr + m * 16 + l15][kg * 8];
#pragma unroll
    for (int n = 0; n < 4; n++) {
      int br = (n < 2) ? (wc * 32 + n * 16) : (64 + wc * 32 + (n - 2) * 16);
      b[n] = *(const short8v*)&Bs[br + l15][kg * 8];
    }
#pragma unroll
    for (int m = 0; m < 4; m++)
#pragma unroll
      for (int n = 0; n < 4; n++)
        acc[m][n] = __builtin_amdgcn_mfma_f32_16x16x32_bf16(a[m], b[n], acc[m][n], 0, 0, 0);
    __syncthreads();
  }
#pragma unroll
  for (int m = 0; m < 4; m++) {
    int rbase = r0 + wr + m * 16 + kg * 4;
#pragma unroll
    for (int reg = 0; reg < 4; reg++) {
      int rr = rbase + reg;
      if (rr < cnt) {
#pragma unroll
        for (int n = 0; n < 2; n++) {
          float g = acc[m][n][reg], u = acc[m][n + 2][reg];
          float a = g / (1.f + expf(-g)) * u;
          act[(size_t)(off + rr) * FDIM + c0 + wc * 32 + n * 16 + l15] = f2bf(a);
        }
      }
    }
  }
}

__global__ __launch_bounds__(256) void k_gemm2_fb(
    const float* __restrict__ wdn, const float* __restrict__ sdn,
    const int* __restrict__ wsI, const unsigned short* __restrict__ act,
    float* __restrict__ out)
{
  const int e = blockIdx.y; const int cnt = wsI[e];
  const int r0 = blockIdx.x * 128; if (r0 >= cnt) return;
  const int off = wsI[16 + e]; const int c0 = blockIdx.z * 128;
  const int* etok = wsI + ETOK_OFF;
  const float* ew = (const float*)(wsI + ETOK_OFF + NENT);
  __shared__ unsigned short As[128][40]; __shared__ unsigned short Bs[128][40];
  const int tid = threadIdx.x, lane = tid & 63, wv = tid >> 6;
  const int wr = (wv >> 1) * 64, wc = wv & 1, kg = lane >> 4, l15 = lane & 15;
  floatx4 acc[4][4] = {};
  for (int k0 = 0; k0 < FDIM; k0 += 32) {
#pragma unroll
    for (int c = tid; c < 512; c += 256) {
      int row = c >> 2, k8 = c & 3;
      int rg = r0 + row; if (rg >= cnt) rg = cnt - 1;
      short8v v = *(const short8v*)&act[(size_t)(off + rg) * FDIM + k0 + k8 * 8];
      *(short8v*)&As[row][k8 * 8] = v;
    }
#pragma unroll
    for (int c = tid; c < 1024; c += 256) {
      int row = c >> 3, k4 = c & 7;
      int gr = c0 + row;
      float s = sdn[e * 128 + (gr >> 7) * 8 + (k0 >> 7)];
      const floatx4 v = *(const floatx4*)&wdn[((size_t)e * HDIM + gr) * FDIM + k0 + k4 * 4];
      ushort4v o = { f2bf(v.x * s), f2bf(v.y * s), f2bf(v.z * s), f2bf(v.w * s) };
      *(ushort4v*)&Bs[row][k4 * 4] = o;
    }
    __syncthreads();
    short8v a[4], b[4];
#pragma unroll
    for (int m = 0; m < 4; m++) a[m] = *(const short8v*)&As[wr + m * 16 + l15][kg * 8];
#pragma unroll
    for (int n = 0; n < 4; n++) b[n] = *(const short8v*)&Bs[wc * 64 + n * 16 + l15][kg * 8];
#pragma unroll
    for (int m = 0; m < 4; m++)
#pragma unroll
      for (int n = 0; n < 4; n++)
        acc[m][n] = __builtin_amdgcn_mfma_f32_16x16x32_bf16(a[m], b[n], acc[m][n], 0, 0, 0);
    __syncthreads();
  }
#pragma unroll
  for (int m = 0; m < 4; m++) {
    int rbase = r0 + wr + m * 16 + kg * 4;
#pragma unroll
    for (int reg = 0; reg < 4; reg++) {
      int rr = rbase + reg;
      if (rr < cnt) {
        int tok = etok[off + rr];
        float ww = ew[off + rr];
#pragma unroll
        for (int n = 0; n < 4; n++)
          atomicAdd(&out[(size_t)tok * HDIM + c0 + wc * 64 + n * 16 + l15], ww * acc[m][n][reg]);
      }
    }
  }
}

extern "C" void kernel_launch(void* const* d_in, const int* in_sizes, int n_in,
                              void* d_out, int out_size, void* d_ws, size_t ws_size,
                              hipStream_t stream) {
  const float* hidden = (const float*)d_in[0];
  const float* tw     = (const float*)d_in[1];
  const int*   ids    = (const int*)d_in[2];
  const float* wgu    = (const float*)d_in[3];
  const float* sgu    = (const float*)d_in[4];
  const float* wdn    = (const float*)d_in[5];
  const float* sdn    = (const float*)d_in[6];
  float* out = (float*)d_out;
  int* wsI = (int*)d_ws;

  hipMemsetAsync(d_ws, 0, 512, stream);
  hipMemsetAsync(d_out, 0, (size_t)T_TOK * HDIM * sizeof(float), stream);
  k_count  <<<16, 256, 0, stream>>>(ids, wsI);
  k_scan   <<<1, 1, 0, stream>>>(wsI);
  k_scatter<<<16, 256, 0, stream>>>(ids, tw, wsI);

  const size_t NEED = 65536ull + (16ull << 20);
  if (ws_size >= NEED) {
    unsigned short* hb  = (unsigned short*)((char*)d_ws + 65536);
    unsigned short* act = hb + (size_t)T_TOK * HDIM;

    k_cast_h<<<2048, 256, 0, stream>>>(hidden, hb);

    dim3 g1(WMAX, 32);
    k_gemm1n<<<g1, 256, 0, stream>>>(hb, wgu, sgu, wsI, act);
    dim3 g2(WMAX, 32);
    k_gemm2n<<<g2, 256, 0, stream>>>(wdn, sdn, wsI, act, out);
  } else {
    unsigned short* act = (unsigned short*)((char*)d_ws + 65536);
    dim3 g1(NENT / 128, NEXP, FDIM / 64);
    k_gemm1_fb<<<g1, 256, 0, stream>>>(hidden, wgu, sgu, wsI, act);
    dim3 g2(NENT / 128, NEXP, HDIM / 128);
    k_gemm2_fb<<<g2, 256, 0, stream>>>(wdn, sdn, wsI, act, out);
  }
}

// Round 11
// 224.118 us; speedup vs baseline: 2.0002x; 2.0002x over previous
//
#include <hip/hip_runtime.h>
#include <hip/hip_bf16.h>

#define T_TOK 2048
#define HDIM  2048
#define FDIM  1024
#define NEXP  8
#define KSEL  2
#define NENT  (T_TOK*KSEL)   // 4096 routing entries
#define WMAX  40             // max 128-row work items (32 + 7 tail + margin)

typedef __attribute__((ext_vector_type(8))) short   short8v;
typedef __attribute__((ext_vector_type(4))) float   floatx4;
typedef __attribute__((ext_vector_type(4))) unsigned short ushort4v;

__device__ __forceinline__ unsigned short f2bf(float f) {
  unsigned int u = __builtin_bit_cast(unsigned int, f);
  u += 0x7FFFu + ((u >> 16) & 1u);
  return (unsigned short)(u >> 16);
}

__device__ __forceinline__ short8v cvt8(floatx4 v0, floatx4 v1, float sc) {
  short8v r = { (short)f2bf(v0.x*sc), (short)f2bf(v0.y*sc),
                (short)f2bf(v0.z*sc), (short)f2bf(v0.w*sc),
                (short)f2bf(v1.x*sc), (short)f2bf(v1.y*sc),
                (short)f2bf(v1.z*sc), (short)f2bf(v1.w*sc) };
  return r;
}

__device__ __forceinline__ void gll16(const void* g, void* l) {
  __builtin_amdgcn_global_load_lds(
      (const __attribute__((address_space(1))) unsigned int*)g,
      (__attribute__((address_space(3))) unsigned int*)l, 16, 0, 0);
}

// ---- workspace layout ----
// wsI[0:8) cnt | wsI[8:16) cursor | wsI[16:24) offsets | wsI[24] nWork
// wsI[48:88) work list (e<<8 | block128)
// wsI[128:128+4096) entry token | (float*)[4096] entry weight
// byte 65536: hb (8 MiB) | wgb (64 MiB) | wdb (32 MiB) | act (8 MiB)
#define ETOK_OFF 128

__global__ void k_count(const int* __restrict__ ids, int* __restrict__ wsI) {
  int g = blockIdx.x * 256 + threadIdx.x;
  if (g < NENT) atomicAdd(&wsI[ids[g] & 7], 1);
}

__global__ void k_scan(int* __restrict__ wsI) {
  int s = 0, nW = 0;
  int* wl = wsI + 48;
  for (int e = 0; e < NEXP; e++) {
    wsI[16 + e] = s;
    int c = wsI[e];
    s += c;
    int nb = (c + 127) >> 7;
    for (int rb = 0; rb < nb; rb++) wl[nW++] = (e << 8) | rb;
  }
  wsI[24] = nW;
}

__global__ void k_scatter(const int* __restrict__ ids, const float* __restrict__ tw,
                          int* __restrict__ wsI) {
  int g = blockIdx.x * 256 + threadIdx.x;
  if (g >= NENT) return;
  int e = ids[g] & 7;
  int pos = atomicAdd(&wsI[8 + e], 1);
  int idx = wsI[16 + e] + pos;
  int*   etok = wsI + ETOK_OFF;
  float* ew   = (float*)(wsI + ETOK_OFF + NENT);
  etok[idx] = g >> 1;
  ew[idx]   = tw[g];
}

// ---- prep: bf16 casts / dequant (streaming, BW-bound) ----
__global__ __launch_bounds__(256) void k_cast_h(const float* __restrict__ h,
                                                unsigned short* __restrict__ o) {
  const int N = T_TOK * HDIM / 8;   // 524288
  int c = blockIdx.x * 256 + threadIdx.x;
  if (c >= N) return;
  const floatx4 v0 = *(const floatx4*)(h + (size_t)c * 8);
  const floatx4 v1 = *(const floatx4*)(h + (size_t)c * 8 + 4);
  *(short8v*)(o + (size_t)c * 8) = cvt8(v0, v1, 1.f);
}

__global__ __launch_bounds__(256) void k_dq_gu(const float* __restrict__ w,
                                               const float* __restrict__ s,
                                               unsigned short* __restrict__ o) {
  const int N = NEXP * 2 * FDIM * HDIM / 8;   // 4194304
  for (int c = blockIdx.x * 256 + threadIdx.x; c < N; c += 8192 * 256) {
    int h8  = c & 255;
    int row = c >> 8;
    int e   = row >> 11;
    int orow = row & 2047;
    float sc = s[e * 256 + (orow >> 7) * 16 + (h8 >> 4)];
    const floatx4 v0 = *(const floatx4*)(w + (size_t)c * 8);
    const floatx4 v1 = *(const floatx4*)(w + (size_t)c * 8 + 4);
    *(short8v*)(o + (size_t)c * 8) = cvt8(v0, v1, sc);
  }
}

__global__ __launch_bounds__(256) void k_dq_dn(const float* __restrict__ w,
                                               const float* __restrict__ s,
                                               unsigned short* __restrict__ o) {
  const int N = NEXP * HDIM * FDIM / 8;       // 2097152
  for (int c = blockIdx.x * 256 + threadIdx.x; c < N; c += 8192 * 256) {
    int f8  = c & 127;
    int row = c >> 7;
    int e   = row >> 11;
    int h   = row & 2047;
    float sc = s[e * 128 + (h >> 7) * 8 + (f8 >> 4)];
    const floatx4 v0 = *(const floatx4*)(w + (size_t)c * 8);
    const floatx4 v1 = *(const floatx4*)(w + (size_t)c * 8 + 4);
    *(short8v*)(o + (size_t)c * 8) = cvt8(v0, v1, sc);
  }
}

// ---- GEMM1: act = silu(h@Wg^T)*(h@Wu^T); BM=128 x 32 act-cols; bf16 gll16 ----
// grid (WMAX, 32): B-tile = 32 gate + 32 up rows, BK=64, 2-barrier loop.
__global__ __launch_bounds__(256, 5) void k_gemm1n(
    const unsigned short* __restrict__ hb,
    const unsigned short* __restrict__ wgb,
    const int* __restrict__ wsI,
    unsigned short* __restrict__ act)
{
  if ((int)blockIdx.x >= wsI[24]) return;
  const int item = wsI[48 + blockIdx.x];
  const int e    = item >> 8;
  const int r0   = (item & 255) << 7;
  const int cnt  = wsI[e];
  const int off  = wsI[16 + e];
  const int c0   = blockIdx.y * 32;          // act col base
  const int* etok = wsI + ETOK_OFF;

  __shared__ unsigned short As[128][64];     // 16 KB
  __shared__ unsigned short Bs[64][64];      // 8 KB

  const int tid = threadIdx.x, lane = tid & 63, w = tid >> 6;
  const int kg = lane >> 4, l15 = lane & 15, lr = lane >> 3, lc = lane & 7;
  const int wr = (w >> 1) * 64, wc = w & 1;

  unsigned int aoff[4];
#pragma unroll
  for (int i = 0; i < 4; i++) {
    int ra  = (w * 4 + i) * 8 + lr;
    int swz = (lc ^ (ra & 7)) * 8;
    int ent = r0 + ra; if (ent >= cnt) ent = cnt - 1;
    aoff[i] = (unsigned)etok[off + ent] * 2048u + (unsigned)swz;
  }
  unsigned int boff[2];
#pragma unroll
  for (int i = 0; i < 2; i++) {
    int rb  = (w * 2 + i) * 8 + lr;          // [0,64)
    int swz = (lc ^ (rb & 7)) * 8;
    int gr  = (rb < 32) ? (c0 + rb) : (1024 + c0 + rb - 32);
    boff[i] = ((unsigned)e * 2048u + (unsigned)gr) * 2048u + (unsigned)swz;
  }

  floatx4 acc[4][2] = {};

  for (int k0 = 0; k0 < HDIM; k0 += 64) {
#pragma unroll
    for (int i = 0; i < 4; i++)
      gll16(hb + aoff[i] + k0, (char*)As + (w * 4 + i) * 1024);
#pragma unroll
    for (int i = 0; i < 2; i++)
      gll16(wgb + boff[i] + k0, (char*)Bs + (w * 2 + i) * 1024);
    __syncthreads();

    const char* Ab = (const char*)As;
    const char* Bb = (const char*)Bs;
#pragma unroll
    for (int ks = 0; ks < 2; ks++) {
      short8v a[4], b[2];
#pragma unroll
      for (int m = 0; m < 4; m++) {
        int r = wr + m * 16 + l15;
        a[m] = *(const short8v*)(Ab + r * 128 + (((ks * 4 + kg) ^ (r & 7)) << 4));
      }
#pragma unroll
      for (int n = 0; n < 2; n++) {
        int rb = n * 32 + wc * 16 + l15;
        b[n] = *(const short8v*)(Bb + rb * 128 + (((ks * 4 + kg) ^ (rb & 7)) << 4));
      }
#pragma unroll
      for (int m = 0; m < 4; m++)
#pragma unroll
        for (int n = 0; n < 2; n++)
          acc[m][n] = __builtin_amdgcn_mfma_f32_16x16x32_bf16(a[m], b[n], acc[m][n], 0, 0, 0);
    }
    __syncthreads();
  }

#pragma unroll
  for (int m = 0; m < 4; m++) {
    int rbase = r0 + wr + m * 16 + kg * 4;
#pragma unroll
    for (int reg = 0; reg < 4; reg++) {
      int rr = rbase + reg;
      if (rr < cnt) {
        float g = acc[m][0][reg];
        float u = acc[m][1][reg];
        float a = g / (1.f + __expf(-g)) * u;
        act[(size_t)(off + rr) * FDIM + c0 + wc * 16 + l15] = f2bf(a);
      }
    }
  }
}

// ---- GEMM2: out[tok] += w_entry * (act @ Wdn^T); BM=128 x 64 h-cols ----
// grid (WMAX, 32): B-tile = 64 rows, BK=64, 2-barrier loop, atomic epilogue.
__global__ __launch_bounds__(256, 5) void k_gemm2n(
    const unsigned short* __restrict__ wdb,
    const int* __restrict__ wsI,
    const unsigned short* __restrict__ act,
    float* __restrict__ out)
{
  if ((int)blockIdx.x >= wsI[24]) return;
  const int item = wsI[48 + blockIdx.x];
  const int e    = item >> 8;
  const int r0   = (item & 255) << 7;
  const int cnt  = wsI[e];
  const int off  = wsI[16 + e];
  const int c0   = blockIdx.y * 64;          // h col base
  const int* etok = wsI + ETOK_OFF;
  const float* ew = (const float*)(wsI + ETOK_OFF + NENT);

  __shared__ unsigned short As[128][64];     // 16 KB
  __shared__ unsigned short Bs[64][64];      // 8 KB

  const int tid = threadIdx.x, lane = tid & 63, w = tid >> 6;
  const int kg = lane >> 4, l15 = lane & 15, lr = lane >> 3, lc = lane & 7;
  const int wr = (w >> 1) * 64, wc = w & 1;

  unsigned int aoff[4];
#pragma unroll
  for (int i = 0; i < 4; i++) {
    int ra  = (w * 4 + i) * 8 + lr;
    int swz = (lc ^ (ra & 7)) * 8;
    int ent = r0 + ra; if (ent >= cnt) ent = cnt - 1;
    aoff[i] = (unsigned)(off + ent) * 1024u + (unsigned)swz;
  }
  unsigned int boff[2];
#pragma unroll
  for (int i = 0; i < 2; i++) {
    int rb  = (w * 2 + i) * 8 + lr;
    int swz = (lc ^ (rb & 7)) * 8;
    boff[i] = ((unsigned)e * 2048u + (unsigned)(c0 + rb)) * 1024u + (unsigned)swz;
  }

  floatx4 acc[4][2] = {};

  for (int k0 = 0; k0 < FDIM; k0 += 64) {
#pragma unroll
    for (int i = 0; i < 4; i++)
      gll16(act + aoff[i] + k0, (char*)As + (w * 4 + i) * 1024);
#pragma unroll
    for (int i = 0; i < 2; i++)
      gll16(wdb + boff[i] + k0, (char*)Bs + (w * 2 + i) * 1024);
    __syncthreads();

    const char* Ab = (const char*)As;
    const char* Bb = (const char*)Bs;
#pragma unroll
    for (int ks = 0; ks < 2; ks++) {
      short8v a[4], b[2];
#pragma unroll
      for (int m = 0; m < 4; m++) {
        int r = wr + m * 16 + l15;
        a[m] = *(const short8v*)(Ab + r * 128 + (((ks * 4 + kg) ^ (r & 7)) << 4));
      }
#pragma unroll
      for (int n = 0; n < 2; n++) {
        int rb = wc * 32 + n * 16 + l15;
        b[n] = *(const short8v*)(Bb + rb * 128 + (((ks * 4 + kg) ^ (rb & 7)) << 4));
      }
#pragma unroll
      for (int m = 0; m < 4; m++)
#pragma unroll
        for (int n = 0; n < 2; n++)
          acc[m][n] = __builtin_amdgcn_mfma_f32_16x16x32_bf16(a[m], b[n], acc[m][n], 0, 0, 0);
    }
    __syncthreads();
  }

#pragma unroll
  for (int m = 0; m < 4; m++) {
    int rbase = r0 + wr + m * 16 + kg * 4;
#pragma unroll
    for (int reg = 0; reg < 4; reg++) {
      int rr = rbase + reg;
      if (rr < cnt) {
        int tok   = etok[off + rr];
        float wgt = ew[off + rr];
#pragma unroll
        for (int n = 0; n < 2; n++)
          atomicAdd(&out[(size_t)tok * HDIM + c0 + wc * 32 + n * 16 + l15],
                    wgt * acc[m][n][reg]);
      }
    }
  }
}

// ================= fallback (round-1 passing kernels) =================
__global__ __launch_bounds__(256) void k_gemm1_fb(
    const float* __restrict__ hidden, const float* __restrict__ wgu,
    const float* __restrict__ sgu, const int* __restrict__ wsI,
    unsigned short* __restrict__ act)
{
  const int e = blockIdx.y; const int cnt = wsI[e];
  const int r0 = blockIdx.x * 128; if (r0 >= cnt) return;
  const int off = wsI[16 + e]; const int c0 = blockIdx.z * 64;
  const int* etok = wsI + ETOK_OFF;
  __shared__ unsigned short As[128][40]; __shared__ unsigned short Bs[128][40];
  const int tid = threadIdx.x, lane = tid & 63, wv = tid >> 6;
  const int wr = (wv >> 1) * 64, wc = wv & 1, kg = lane >> 4, l15 = lane & 15;
  floatx4 acc[4][4] = {};
  for (int k0 = 0; k0 < HDIM; k0 += 32) {
#pragma unroll
    for (int c = tid; c < 1024; c += 256) {
      int row = c >> 3, k4 = c & 7;
      int rg = r0 + row; if (rg >= cnt) rg = cnt - 1;
      int tok = etok[off + rg];
      const floatx4 v = *(const floatx4*)&hidden[(size_t)tok * HDIM + k0 + k4 * 4];
      ushort4v o = { f2bf(v.x), f2bf(v.y), f2bf(v.z), f2bf(v.w) };
      *(ushort4v*)&As[row][k4 * 4] = o;
    }
#pragma unroll
    for (int c = tid; c < 1024; c += 256) {
      int row = c >> 3, k4 = c & 7;
      int gr = (row < 64) ? (c0 + row) : (FDIM + c0 + row - 64);
      float s = sgu[e * 256 + (gr >> 7) * 16 + (k0 >> 7)];
      const floatx4 v = *(const floatx4*)&wgu[((size_t)e * 2048 + gr) * HDIM + k0 + k4 * 4];
      ushort4v o = { f2bf(v.x * s), f2bf(v.y * s), f2bf(v.z * s), f2bf(v.w * s) };
      *(ushort4v*)&Bs[row][k4 * 4] = o;
    }
    __syncthreads();
    short8v a[4], b[4];
#pragma unroll
    for (int m = 0; m < 4; m++) a[m] = *(const short8v*)&As[wr + m * 16 + l15][kg * 8];
#pragma unroll
    for (int n = 0; n < 4; n++) {
      int br = (n < 2) ? (wc * 32 + n * 16) : (64 + wc * 32 + (n - 2) * 16);
      b[n] = *(const short8v*)&Bs[br + l15][kg * 8];
    }
#pragma unroll
    for (int m = 0; m < 4; m++)
#pragma unroll
      for (int n = 0; n < 4; n++)
        acc[m][n] = __builtin_amdgcn_mfma_f32_16x16x32_bf16(a[m], b[n], acc[m][n], 0, 0, 0);
    __syncthreads();
  }
#pragma unroll
  for (int m = 0; m < 4; m++) {
    int rbase = r0 + wr + m * 16 + kg * 4;
#pragma unroll
    for (int reg = 0; reg < 4; reg++) {
      int rr = rbase + reg;
      if (rr < cnt) {
#pragma unroll
        for (int n = 0; n < 2; n++) {
          float g = acc[m][n][reg], u = acc[m][n + 2][reg];
          float a = g / (1.f + expf(-g)) * u;
          act[(size_t)(off + rr) * FDIM + c0 + wc * 32 + n * 16 + l15] = f2bf(a);
        }
      }
    }
  }
}

__global__ __launch_bounds__(256) void k_gemm2_fb(
    const float* __restrict__ wdn, const float* __restrict__ sdn,
    const int* __restrict__ wsI, const unsigned short* __restrict__ act,
    float* __restrict__ out)
{
  const int e = blockIdx.y; const int cnt = wsI[e];
  const int r0 = blockIdx.x * 128; if (r0 >= cnt) return;
  const int off = wsI[16 + e]; const int c0 = blockIdx.z * 128;
  const int* etok = wsI + ETOK_OFF;
  const float* ew = (const float*)(wsI + ETOK_OFF + NENT);
  __shared__ unsigned short As[128][40]; __shared__ unsigned short Bs[128][40];
  const int tid = threadIdx.x, lane = tid & 63, wv = tid >> 6;
  const int wr = (wv >> 1) * 64, wc = wv & 1, kg = lane >> 4, l15 = lane & 15;
  floatx4 acc[4][4] = {};
  for (int k0 = 0; k0 < FDIM; k0 += 32) {
#pragma unroll
    for (int c = tid; c < 512; c += 256) {
      int row = c >> 2, k8 = c & 3;
      int rg = r0 + row; if (rg >= cnt) rg = cnt - 1;
      short8v v = *(const short8v*)&act[(size_t)(off + rg) * FDIM + k0 + k8 * 8];
      *(short8v*)&As[row][k8 * 8] = v;
    }
#pragma unroll
    for (int c = tid; c < 1024; c += 256) {
      int row = c >> 3, k4 = c & 7;
      int gr = c0 + row;
      float s = sdn[e * 128 + (gr >> 7) * 8 + (k0 >> 7)];
      const floatx4 v = *(const floatx4*)&wdn[((size_t)e * HDIM + gr) * FDIM + k0 + k4 * 4];
      ushort4v o = { f2bf(v.x * s), f2bf(v.y * s), f2bf(v.z * s), f2bf(v.w * s) };
      *(ushort4v*)&Bs[row][k4 * 4] = o;
    }
    __syncthreads();
    short8v a[4], b[4];
#pragma unroll
    for (int m = 0; m < 4; m++) a[m] = *(const short8v*)&As[wr + m * 16 + l15][kg * 8];
#pragma unroll
    for (int n = 0; n < 4; n++) b[n] = *(const short8v*)&Bs[wc * 64 + n * 16 + l15][kg * 8];
#pragma unroll
    for (int m = 0; m < 4; m++)
#pragma unroll
      for (int n = 0; n < 4; n++)
        acc[m][n] = __builtin_amdgcn_mfma_f32_16x16x32_bf16(a[m], b[n], acc[m][n], 0, 0, 0);
    __syncthreads();
  }
#pragma unroll
  for (int m = 0; m < 4; m++) {
    int rbase = r0 + wr + m * 16 + kg * 4;
#pragma unroll
    for (int reg = 0; reg < 4; reg++) {
      int rr = rbase + reg;
      if (rr < cnt) {
        int tok = etok[off + rr];
        float ww = ew[off + rr];
#pragma unroll
        for (int n = 0; n < 4; n++)
          atomicAdd(&out[(size_t)tok * HDIM + c0 + wc * 64 + n * 16 + l15], ww * acc[m][n][reg]);
      }
    }
  }
}

extern "C" void kernel_launch(void* const* d_in, const int* in_sizes, int n_in,
                              void* d_out, int out_size, void* d_ws, size_t ws_size,
                              hipStream_t stream) {
  const float* hidden = (const float*)d_in[0];
  const float* tw     = (const float*)d_in[1];
  const int*   ids    = (const int*)d_in[2];
  const float* wgu    = (const float*)d_in[3];
  const float* sgu    = (const float*)d_in[4];
  const float* wdn    = (const float*)d_in[5];
  const float* sdn    = (const float*)d_in[6];
  float* out = (float*)d_out;
  int* wsI = (int*)d_ws;

  hipMemsetAsync(d_ws, 0, 512, stream);
  hipMemsetAsync(d_out, 0, (size_t)T_TOK * HDIM * sizeof(float), stream);
  k_count  <<<16, 256, 0, stream>>>(ids, wsI);
  k_scan   <<<1, 1, 0, stream>>>(wsI);
  k_scatter<<<16, 256, 0, stream>>>(ids, tw, wsI);

  const size_t NEED = 65536ull + (113ull << 20);
  if (ws_size >= NEED) {
    unsigned short* hb  = (unsigned short*)((char*)d_ws + 65536);
    unsigned short* wgb = hb  + (size_t)T_TOK * HDIM;
    unsigned short* wdb = wgb + (size_t)NEXP * 2 * FDIM * HDIM;
    unsigned short* act = wdb + (size_t)NEXP * HDIM * FDIM;

    k_cast_h<<<T_TOK * HDIM / 8 / 256, 256, 0, stream>>>(hidden, hb);
    k_dq_gu <<<8192, 256, 0, stream>>>(wgu, sgu, wgb);
    k_dq_dn <<<8192, 256, 0, stream>>>(wdn, sdn, wdb);

    dim3 g1(WMAX, 32);
    k_gemm1n<<<g1, 256, 0, stream>>>(hb, wgb, wsI, act);
    dim3 g2(WMAX, 32);
    k_gemm2n<<<g2, 256, 0, stream>>>(wdb, wsI, act, out);
  } else {
    unsigned short* act = (unsigned short*)((char*)d_ws + 65536);
    dim3 g1(NENT / 128, NEXP, FDIM / 64);
    k_gemm1_fb<<<g1, 256, 0, stream>>>(hidden, wgu, sgu, wsI, act);
    dim3 g2(NENT / 128, NEXP, HDIM / 128);
    k_gemm2_fb<<<g2, 256, 0, stream>>>(wdn, sdn, wsI, act, out);
  }
}